// Round 5
// baseline (236.448 us; speedup 1.0000x reference)
//
#include <hip/hip_runtime.h>
#include <math.h>

// ---------------------------------------------------------------------------
// QCNN forward, split kernels (cooperative launch rejected by runtime at this
// LDS footprint — R4):
//   expm -> layer0 gates (2 LDS passes, 3-gate register phases) ->
//   pool0 + layer1 gates + pooled outer products -> reduce+tail.
// Bit convention: qubit q <-> address bit (19-q).  Gate digit r = 2*b(pa)+b(pb).
// pool LDS layout: w[t_lo*1056 + s*33 + u]  (odd stride 33).
// ---------------------------------------------------------------------------

__device__ __forceinline__ float2 cmul(float2 a, float2 b) {
  return make_float2(a.x * b.x - a.y * b.y, a.x * b.y + a.y * b.x);
}
__device__ __forceinline__ float2 cmadd(float2 acc, float2 a, float2 b) {
  acc.x = fmaf(a.x, b.x, fmaf(-a.y, b.y, acc.x));
  acc.y = fmaf(a.x, b.y, fmaf(a.y, b.x, acc.y));
  return acc;
}
// acc += a * conj(b)
__device__ __forceinline__ float2 cmaddc(float2 acc, float2 a, float2 b) {
  acc.x = fmaf(a.x, b.x, fmaf(a.y, b.y, acc.x));
  acc.y = fmaf(a.y, b.x, fmaf(-a.x, b.y, acc.y));
  return acc;
}
__device__ __forceinline__ int pad(int e) { return e + (e >> 4); }

__device__ __forceinline__ unsigned spread(unsigned v) {  // bit j -> 2j
  v = (v | (v << 8)) & 0x00FF00FFu;
  v = (v | (v << 4)) & 0x0F0F0F0Fu;
  v = (v | (v << 2)) & 0x33333333u;
  v = (v | (v << 1)) & 0x55555555u;
  return v;
}
__device__ __forceinline__ unsigned spread2(unsigned v) { return spread(spread(v)); }
__device__ __forceinline__ int ins(int x, int p) {  // insert zero bit at p
  return ((x >> p) << (p + 1)) | (x & ((1 << p) - 1));
}

__device__ __forceinline__ void gate4(float2& v0, float2& v1, float2& v2, float2& v3,
                                      const float2 (&U)[16]) {
  float2 n0 = cmul(U[0], v0);  n0 = cmadd(n0, U[1], v1);  n0 = cmadd(n0, U[2], v2);  n0 = cmadd(n0, U[3], v3);
  float2 n1 = cmul(U[4], v0);  n1 = cmadd(n1, U[5], v1);  n1 = cmadd(n1, U[6], v2);  n1 = cmadd(n1, U[7], v3);
  float2 n2 = cmul(U[8], v0);  n2 = cmadd(n2, U[9], v1);  n2 = cmadd(n2, U[10], v2); n2 = cmadd(n2, U[11], v3);
  float2 n3 = cmul(U[12], v0); n3 = cmadd(n3, U[13], v1); n3 = cmadd(n3, U[14], v2); n3 = cmadd(n3, U[15], v3);
  v0 = n0; v1 = n1; v2 = n2; v3 = n3;
}

// NG gates on a 16-elem register block (v index bit k <-> local bit k):
// (l1,l0), (l3,l2), and if NG==3 the sandwiched odd gate (l2,l1).
template <int NG>
__device__ __forceinline__ void gate16n(float2 (&v)[16], const float2 (&U)[16]) {
#pragma unroll
  for (int g = 0; g < 4; g++)
    gate4(v[g * 4 + 0], v[g * 4 + 1], v[g * 4 + 2], v[g * 4 + 3], U);
#pragma unroll
  for (int lo = 0; lo < 4; lo++)
    gate4(v[lo], v[lo + 4], v[lo + 8], v[lo + 12], U);
  if (NG == 3) {
#pragma unroll
    for (int b3 = 0; b3 < 2; b3++)
#pragma unroll
      for (int b0 = 0; b0 < 2; b0++) {
        int j = b3 * 8 + b0;
        gate4(v[j], v[j + 2], v[j + 4], v[j + 6], U);
      }
  }
}

// single 2-qubit gate (pa,pb) over padded 2^13 LDS tile
__device__ __forceinline__ void apply_gate_tile13(float2* t, const float2 (&U)[16],
                                                  int pa, int pb, int tid) {
  int p0 = pa < pb ? pa : pb;
  int p1 = pa < pb ? pb : pa;
  int m0 = (1 << p0) - 1, m1 = (1 << p1) - 1;
  int ia = 1 << pa, ib = 1 << pb;
#pragma unroll
  for (int g = tid; g < 2048; g += 256) {
    int idx = ((g & ~m0) << 1) | (g & m0);
    idx = ((idx & ~m1) << 1) | (idx & m1);
    int e0 = pad(idx), e1 = pad(idx | ib), e2 = pad(idx | ia), e3 = pad(idx | ia | ib);
    float2 v0 = t[e0], v1 = t[e1], v2 = t[e2], v3 = t[e3];
    gate4(v0, v1, v2, v3, U);
    t[e0] = v0; t[e1] = v1; t[e2] = v2; t[e3] = v3;
  }
}

// register phase over tile bits {p0<p1<p2<p3}: gates (p1,p0),(p3,p2)[,(p2,p1)]
template <int NG>
__device__ __forceinline__ void phase4_l0(float2* t, const float2 (&U)[16],
                                          int p0, int p1, int p2, int p3, int tid) {
  int o0 = 1 << p0, o1 = 1 << p1, o2 = 1 << p2, o3 = 1 << p3;
#pragma unroll
  for (int it = 0; it < 2; it++) {
    int h = tid + it * 256;
    int idx = ins(ins(ins(ins(h, p0), p1), p2), p3);
    float2 v[16];
#pragma unroll
    for (int j = 0; j < 16; j++) {
      int off = ((j & 1) ? o0 : 0) + ((j & 2) ? o1 : 0) + ((j & 4) ? o2 : 0) + ((j & 8) ? o3 : 0);
      v[j] = t[pad(idx + off)];
    }
    gate16n<NG>(v, U);
#pragma unroll
    for (int j = 0; j < 16; j++) {
      int off = ((j & 1) ? o0 : 0) + ((j & 2) ? o1 : 0) + ((j & 4) ? o2 : 0) + ((j & 8) ? o3 : 0);
      t[pad(idx + off)] = v[j];
    }
  }
}

// pool register phase: removes u-bits {a_lo<a_hi}, s-bits {c_lo<c_hi};
// o0..o3 = flat strides of local bits 0..3
template <int NG>
__device__ __forceinline__ void phase4_pool(float2* w, const float2 (&U)[16],
                                            int a_lo, int a_hi, int c_lo, int c_hi,
                                            int o0, int o1, int o2, int o3, int tid) {
#pragma unroll
  for (int it = 0; it < 2; it++) {
    int h = tid + it * 256;
    int uu = h & 7, ss = (h >> 3) & 7, t_lo = h >> 6;
    int u = ins(ins(uu, a_lo), a_hi);
    int s = ins(ins(ss, c_lo), c_hi);
    int base = t_lo * 1056 + s * 33 + u;
    float2 v[16];
#pragma unroll
    for (int j = 0; j < 16; j++) {
      int off = ((j & 1) ? o0 : 0) + ((j & 2) ? o1 : 0) + ((j & 4) ? o2 : 0) + ((j & 8) ? o3 : 0);
      v[j] = w[base + off];
    }
    gate16n<NG>(v, U);
#pragma unroll
    for (int j = 0; j < 16; j++) {
      int off = ((j & 1) ? o0 : 0) + ((j & 2) ? o1 : 0) + ((j & 4) ? o2 : 0) + ((j & 8) ? o3 : 0);
      w[base + off] = v[j];
    }
  }
}

// pool P3: gates {1,0} then {2,1} on locals [o0=1(u0=i0), o1=33(s0=i1), o2=2(u1=i2)]
__device__ __forceinline__ void pool_p3(float2* w, const float2 (&U)[16], int tid) {
#pragma unroll
  for (int it = 0; it < 4; it++) {
    int h = tid + it * 256;
    int uu = h & 7, ss = (h >> 3) & 15, t_lo = h >> 7;
    int base = t_lo * 1056 + (ss << 1) * 33 + (uu << 2);
    float2 v[8];
    v[0] = w[base];      v[1] = w[base + 1];
    v[4] = w[base + 2];  v[5] = w[base + 3];
    v[2] = w[base + 33]; v[3] = w[base + 34];
    v[6] = w[base + 35]; v[7] = w[base + 36];
    gate4(v[0], v[1], v[2], v[3], U);   // {1,0}, u1=0
    gate4(v[4], v[5], v[6], v[7], U);   // {1,0}, u1=1
    gate4(v[0], v[2], v[4], v[6], U);   // {2,1}, u0=0
    gate4(v[1], v[3], v[5], v[7], U);   // {2,1}, u0=1
    w[base] = v[0];      w[base + 1] = v[1];
    w[base + 2] = v[4];  w[base + 3] = v[5];
    w[base + 33] = v[2]; w[base + 34] = v[3];
    w[base + 35] = v[6]; w[base + 36] = v[7];
  }
}

// ---------------------------------------------------------------------------
// Kernel A: U[l] = expm(A - A^H), fp64, lane-parallel (16 lanes per matrix)
// ---------------------------------------------------------------------------
__global__ __launch_bounds__(320) void expm_kernel(const float* __restrict__ Hre,
                                                   const float* __restrict__ Him,
                                                   float2* __restrict__ Uout) {
  int wave = threadIdx.x >> 6;
  int lane = threadIdx.x & 63;
  if (wave >= 5 || lane >= 16) return;
  int l = wave;
  int r = lane >> 2, c = lane & 3;
  double tr = (double)Hre[l * 16 + r * 4 + c] - (double)Hre[l * 16 + c * 4 + r];
  double ti = (double)Him[l * 16 + r * 4 + c] + (double)Him[l * 16 + c * 4 + r];
  double a = sqrt(tr * tr + ti * ti);
  a += __shfl_xor(a, 1, 64);
  a += __shfl_xor(a, 2, 64);
  double nrm = fmax(a, __shfl_xor(a, 4, 64));
  nrm = fmax(nrm, __shfl_xor(nrm, 8, 64));
  int s = 0;
  while (nrm > 0.25 && s < 60) { nrm *= 0.5; s++; }
  double sc = ldexp(1.0, -s);
  tr *= sc; ti *= sc;
  double id = (r == c) ? 1.0 : 0.0;
  double er = id, ei = 0.0, pr = id, pi = 0.0;
  for (int k = 1; k <= 16; k++) {
    double qr = 0.0, qi = 0.0;
#pragma unroll
    for (int m = 0; m < 4; m++) {
      double pmr = __shfl(pr, r * 4 + m, 64);
      double pmi = __shfl(pi, r * 4 + m, 64);
      double tmr = __shfl(tr, m * 4 + c, 64);
      double tmi = __shfl(ti, m * 4 + c, 64);
      qr = fma(pmr, tmr, fma(-pmi, tmi, qr));
      qi = fma(pmr, tmi, fma(pmi, tmr, qi));
    }
    double inv = 1.0 / (double)k;
    pr = qr * inv; pi = qi * inv;
    er += pr; ei += pi;
  }
  for (int it = 0; it < s; it++) {
    double qr = 0.0, qi = 0.0;
#pragma unroll
    for (int m = 0; m < 4; m++) {
      double amr = __shfl(er, r * 4 + m, 64);
      double ami = __shfl(ei, r * 4 + m, 64);
      double bmr = __shfl(er, m * 4 + c, 64);
      double bmi = __shfl(ei, m * 4 + c, 64);
      qr = fma(amr, bmr, fma(-ami, bmi, qr));
      qi = fma(amr, bmi, fma(ami, bmr, qi));
    }
    er = qr; ei = qi;
  }
  Uout[l * 16 + lane] = make_float2((float)er, (float)ei);
}

// ---------------------------------------------------------------------------
// Kernel B: layer-0 pass 1. Tile = addr bits 0..12; 11 gates in 4 round-trips.
// ---------------------------------------------------------------------------
__global__ __launch_bounds__(256) void l0_pass1(const float* __restrict__ pre,
                                                const float* __restrict__ pim,
                                                const float2* __restrict__ Umat,
                                                float2* __restrict__ state) {
  extern __shared__ float2 tile[];
  int tid = threadIdx.x;
  int bid = blockIdx.x;
  int b = bid >> 7, hi = bid & 127;
  size_t base = ((size_t)b << 20) | ((size_t)hi << 13);
  float2 U[16];
#pragma unroll
  for (int k = 0; k < 16; k++) U[k] = Umat[k];
  for (int e = tid; e < 8192; e += 256)
    tile[pad(e)] = make_float2(pre[base + e], pim[base + e]);
  __syncthreads();
  phase4_l0<3>(tile, U, 0, 1, 2, 3, tid);   __syncthreads(); // {1,0},{3,2},{2,1}
  phase4_l0<3>(tile, U, 4, 5, 6, 7, tid);   __syncthreads(); // {5,4},{7,6},{6,5}
  phase4_l0<3>(tile, U, 8, 9, 10, 11, tid); __syncthreads(); // {9,8},{11,10},{10,9}
  phase4_l0<2>(tile, U, 3, 4, 7, 8, tid);   __syncthreads(); // {4,3},{8,7}
  for (int e = tid; e < 8192; e += 256) state[base + e] = tile[pad(e)];
}

// ---------------------------------------------------------------------------
// Kernel C: layer-0 pass 2. Tile = bits {0..3} U {11..19}; 9 gates in 4 RTs.
// ---------------------------------------------------------------------------
__global__ __launch_bounds__(256) void l0_pass2(const float2* __restrict__ Umat,
                                                float2* __restrict__ state) {
  extern __shared__ float2 tile[];
  int tid = threadIdx.x;
  int bid = blockIdx.x;
  int b = bid >> 7, mid = bid & 127;
  size_t base = ((size_t)b << 20) | ((size_t)mid << 4);
  float2 U[16];
#pragma unroll
  for (int k = 0; k < 16; k++) U[k] = Umat[k];
  for (int e = tid; e < 8192; e += 256) {
    size_t a = base + (((size_t)(e >> 4)) << 11) + (size_t)(e & 15);
    tile[pad(e)] = state[a];
  }
  __syncthreads();
  phase4_l0<3>(tile, U, 5, 6, 7, 8, tid);    __syncthreads(); // {6,5},{8,7},{7,6}
  phase4_l0<3>(tile, U, 9, 10, 11, 12, tid); __syncthreads(); // {10,9},{12,11},{11,10}
  phase4_l0<2>(tile, U, 4, 5, 8, 9, tid);    __syncthreads(); // {5,4},{9,8}
  apply_gate_tile13(tile, U, 0, 12, tid);    __syncthreads(); // wrap {0,12}
  for (int e = tid; e < 8192; e += 256) {
    size_t a = base + (((size_t)(e >> 4)) << 11) + (size_t)(e & 15);
    state[a] = tile[pad(e)];
  }
}

// ---------------------------------------------------------------------------
// Kernel D: pool0 + layer1 gates (4 RTs) + pool1 partials.
// ---------------------------------------------------------------------------
__global__ __launch_bounds__(256) void pool_l1(const float2* __restrict__ Umat,
                                               const float2* __restrict__ state,
                                               float2* __restrict__ partial) {
  extern __shared__ float2 w[];  // 8448 float2
  int tid = threadIdx.x;
  int bid = blockIdx.x;
  int b = bid >> 7, thi = bid & 127;
  size_t bbase = (size_t)b << 20;
  float2 U[16];
#pragma unroll
  for (int k = 0; k < 16; k++) U[k] = Umat[16 + k];
  unsigned tbase = spread((unsigned)(thi << 3)) << 1;
  for (int e = tid; e < 8192; e += 256) {
    int u = e & 31, s = (e >> 5) & 31, t_lo = e >> 10;
    unsigned addr = tbase | (spread((unsigned)t_lo) << 1) | spread2((unsigned)u)
                  | (spread2((unsigned)s) << 2);
    w[t_lo * 1056 + s * 33 + u] = state[bbase + (size_t)addr];
  }
  __syncthreads();
  // i-bit even 2j = u-bit j (stride 2^j); i-bit odd 2j+1 = s-bit j (stride 33*2^j)
  phase4_pool<3>(w, U, 3, 4, 3, 4, 8, 264, 16, 528, tid); __syncthreads(); // {7,6},{9,8},{8,7}
  phase4_pool<3>(w, U, 1, 2, 1, 2, 2, 66, 4, 132, tid);   __syncthreads(); // {3,2},{5,4},{4,3}
  pool_p3(w, U, tid);                                     __syncthreads(); // {1,0},{2,1}
  phase4_pool<2>(w, U, 0, 3, 2, 4, 132, 8, 528, 1, tid);  __syncthreads(); // {6,5},{0,9}
  // pool1: rho2[u,v] = sum_{t,s} w[t,s,u]*conj(w[t,s,v]); 4x4 per lane
  int wv = tid >> 6, lane = tid & 63;
  int u0 = (lane >> 3) << 2, v0 = (lane & 7) << 2;
  float2 acc[4][4];
#pragma unroll
  for (int i = 0; i < 4; i++)
#pragma unroll
    for (int j = 0; j < 4; j++) acc[i][j] = make_float2(0.f, 0.f);
  for (int tl = 0; tl < 2; tl++) {
    int tb = (wv * 2 + tl) * 1056;
#pragma unroll 4
    for (int s = 0; s < 32; s++) {
      int row = tb + s * 33;
      float2 x[4], y[4];
#pragma unroll
      for (int i = 0; i < 4; i++) { x[i] = w[row + u0 + i]; y[i] = w[row + v0 + i]; }
#pragma unroll
      for (int i = 0; i < 4; i++)
#pragma unroll
        for (int j = 0; j < 4; j++) acc[i][j] = cmaddc(acc[i][j], x[i], y[j]);
    }
  }
  __syncthreads();  // w dead; reuse for cross-wave reduce
  if (wv > 0) {
#pragma unroll
    for (int i = 0; i < 4; i++)
#pragma unroll
      for (int j = 0; j < 4; j++)
        w[(wv - 1) * 1024 + (u0 + i) * 32 + (v0 + j)] = acc[i][j];
  }
  __syncthreads();
  if (wv == 0) {
    float2* outp = partial + ((size_t)bid << 10);
#pragma unroll
    for (int i = 0; i < 4; i++)
#pragma unroll
      for (int j = 0; j < 4; j++) {
        float2 a = acc[i][j];
#pragma unroll
        for (int k = 0; k < 3; k++) {
          float2 o = w[k * 1024 + (u0 + i) * 32 + (v0 + j)];
          a.x += o.x; a.y += o.y;
        }
        outp[(u0 + i) * 32 + (v0 + j)] = a;
      }
  }
}

// ---------------------------------------------------------------------------
// Kernel E: per-batch reduce of 128 partials + layers 2..4 + measure.
// One block per batch.
// ---------------------------------------------------------------------------
__global__ __launch_bounds__(256) void finish(const float2* __restrict__ Umat,
                                              const float* __restrict__ partial,
                                              float* __restrict__ out) {
  __shared__ float2 rho[1024];
  __shared__ float2 r3s[64];
  __shared__ float2 r4s[16];
  int tid = threadIdx.x;
  int b = blockIdx.x;
  // reduce 128 partial tiles (2048 floats each) for this batch
  float* rt = (float*)rho;
#pragma unroll
  for (int k = 0; k < 8; k++) {
    int p = tid + k * 256;
    float acc = 0.f;
    for (int h = 0; h < 128; h++)
      acc += partial[(((size_t)(b * 128 + h)) << 11) + (size_t)p];
    rt[p] = acc;
  }
  __syncthreads();

  float2 U[16], Uc[16];
#pragma unroll
  for (int k = 0; k < 16; k++) { U[k] = Umat[32 + k]; Uc[k] = make_float2(U[k].x, -U[k].y); }
  const int gl2[4][2] = {{4,3},{2,1},{3,2},{1,0}};
#pragma unroll
  for (int gi = 0; gi < 4; gi++) {
    int pa = gl2[gi][0], pb = gl2[gi][1];
    int p0 = pa < pb ? pa : pb, p1 = pa < pb ? pb : pa;
    int m0 = (1 << p0) - 1, m1 = (1 << p1) - 1;
    int ia = 1 << pa, ib = 1 << pb;
    {
      int j = tid >> 3, g = tid & 7;
      int idx = ((g & ~m0) << 1) | (g & m0);
      idx = ((idx & ~m1) << 1) | (idx & m1);
      float2 v0 = rho[idx * 32 + j], v1 = rho[(idx | ib) * 32 + j];
      float2 v2 = rho[(idx | ia) * 32 + j], v3 = rho[(idx | ia | ib) * 32 + j];
      gate4(v0, v1, v2, v3, U);
      rho[idx * 32 + j] = v0; rho[(idx | ib) * 32 + j] = v1;
      rho[(idx | ia) * 32 + j] = v2; rho[(idx | ia | ib) * 32 + j] = v3;
    }
    __syncthreads();
    {
      int i = tid >> 3, g = tid & 7;
      int idx = ((g & ~m0) << 1) | (g & m0);
      idx = ((idx & ~m1) << 1) | (idx & m1);
      float2 v0 = rho[i * 32 + idx], v1 = rho[i * 32 + (idx | ib)];
      float2 v2 = rho[i * 32 + (idx | ia)], v3 = rho[i * 32 + (idx | ia | ib)];
      gate4(v0, v1, v2, v3, Uc);
      rho[i * 32 + idx] = v0; rho[i * 32 + (idx | ib)] = v1;
      rho[i * 32 + (idx | ia)] = v2; rho[i * 32 + (idx | ia | ib)] = v3;
    }
    __syncthreads();
  }
  if (tid < 64) {
    int u = tid >> 3, v = tid & 7;
    float2 acc = {0.f, 0.f};
#pragma unroll
    for (int s = 0; s < 4; s++) {
      int iu = ((s >> 1) << 4) | ((u >> 2) << 3) | ((s & 1) << 2) | (((u >> 1) & 1) << 1) | (u & 1);
      int iv = ((s >> 1) << 4) | ((v >> 2) << 3) | ((s & 1) << 2) | (((v >> 1) & 1) << 1) | (v & 1);
      float2 x = rho[iu * 32 + iv];
      acc.x += x.x; acc.y += x.y;
    }
    r3s[u * 8 + v] = acc;
  }
  __syncthreads();

#pragma unroll
  for (int k = 0; k < 16; k++) { U[k] = Umat[48 + k]; Uc[k] = make_float2(U[k].x, -U[k].y); }
  const int gl3[2][2] = {{2,1},{1,0}};
#pragma unroll
  for (int gi = 0; gi < 2; gi++) {
    int pa = gl3[gi][0], pb = gl3[gi][1];
    int p0 = pa < pb ? pa : pb, p1 = pa < pb ? pb : pa;
    int m0 = (1 << p0) - 1, m1 = (1 << p1) - 1;
    int ia = 1 << pa, ib = 1 << pb;
    if (tid < 16) {
      int j = tid >> 1, g = tid & 1;
      int idx = ((g & ~m0) << 1) | (g & m0);
      idx = ((idx & ~m1) << 1) | (idx & m1);
      float2 v0 = r3s[idx * 8 + j], v1 = r3s[(idx | ib) * 8 + j];
      float2 v2 = r3s[(idx | ia) * 8 + j], v3 = r3s[(idx | ia | ib) * 8 + j];
      gate4(v0, v1, v2, v3, U);
      r3s[idx * 8 + j] = v0; r3s[(idx | ib) * 8 + j] = v1;
      r3s[(idx | ia) * 8 + j] = v2; r3s[(idx | ia | ib) * 8 + j] = v3;
    }
    __syncthreads();
    if (tid < 16) {
      int i = tid >> 1, g = tid & 1;
      int idx = ((g & ~m0) << 1) | (g & m0);
      idx = ((idx & ~m1) << 1) | (idx & m1);
      float2 v0 = r3s[i * 8 + idx], v1 = r3s[i * 8 + (idx | ib)];
      float2 v2 = r3s[i * 8 + (idx | ia)], v3 = r3s[i * 8 + (idx | ia | ib)];
      gate4(v0, v1, v2, v3, Uc);
      r3s[i * 8 + idx] = v0; r3s[i * 8 + (idx | ib)] = v1;
      r3s[i * 8 + (idx | ia)] = v2; r3s[i * 8 + (idx | ia | ib)] = v3;
    }
    __syncthreads();
  }
  if (tid < 16) {
    int u = tid >> 2, v = tid & 3;
    float2 acc = {0.f, 0.f};
#pragma unroll
    for (int s = 0; s < 2; s++) {
      float2 x = r3s[((s << 2) | u) * 8 + ((s << 2) | v)];
      acc.x += x.x; acc.y += x.y;
    }
    r4s[u * 4 + v] = acc;
  }
  __syncthreads();

#pragma unroll
  for (int k = 0; k < 16; k++) { U[k] = Umat[64 + k]; Uc[k] = make_float2(U[k].x, -U[k].y); }
  if (tid < 4) {
    int j = tid;
    float2 v0 = r4s[0 * 4 + j], v1 = r4s[1 * 4 + j], v2 = r4s[2 * 4 + j], v3 = r4s[3 * 4 + j];
    gate4(v0, v1, v2, v3, U);
    r4s[0 * 4 + j] = v0; r4s[1 * 4 + j] = v1; r4s[2 * 4 + j] = v2; r4s[3 * 4 + j] = v3;
  }
  __syncthreads();
  if (tid < 4) {
    int i = tid;
    float2 v0 = r4s[i * 4 + 0], v1 = r4s[i * 4 + 1], v2 = r4s[i * 4 + 2], v3 = r4s[i * 4 + 3];
    gate4(v0, v1, v2, v3, Uc);
    r4s[i * 4 + 0] = v0; r4s[i * 4 + 1] = v1; r4s[i * 4 + 2] = v2; r4s[i * 4 + 3] = v3;
  }
  __syncthreads();
  if (tid == 0) out[b] = r4s[0].x + r4s[10].x;
}

// ---------------------------------------------------------------------------
extern "C" void kernel_launch(void* const* d_in, const int* in_sizes, int n_in,
                              void* d_out, int out_size, void* d_ws, size_t ws_size,
                              hipStream_t stream) {
  const float* psi_re = (const float*)d_in[0];
  const float* psi_im = (const float*)d_in[1];
  const float* H_re = (const float*)d_in[2];
  const float* H_im = (const float*)d_in[3];
  float* out = (float*)d_out;

  char* ws = (char*)d_ws;
  float2* Umat = (float2*)ws;                                   // 5*16 float2
  float2* state = (float2*)(ws + 4096);                         // 32 MB
  float* partial = (float*)(ws + 4096 + ((size_t)1 << 25));     // 4 MB

  const size_t LDS_L0 = 8704 * sizeof(float2);    // padded 8192
  const size_t LDS_POOL = 8448 * sizeof(float2);  // 8*1056 stride-33 rows

  hipLaunchKernelGGL(expm_kernel, dim3(1), dim3(320), 0, stream, H_re, H_im, Umat);
  hipLaunchKernelGGL(l0_pass1, dim3(512), dim3(256), LDS_L0, stream,
                     psi_re, psi_im, Umat, state);
  hipLaunchKernelGGL(l0_pass2, dim3(512), dim3(256), LDS_L0, stream, Umat, state);
  hipLaunchKernelGGL(pool_l1, dim3(512), dim3(256), LDS_POOL, stream,
                     Umat, state, (float2*)partial);
  hipLaunchKernelGGL(finish, dim3(4), dim3(256), 0, stream, Umat, partial, out);
}

// Round 6
// 189.484 us; speedup vs baseline: 1.2479x; 1.2479x over previous
//
#include <hip/hip_runtime.h>
#include <math.h>

// ---------------------------------------------------------------------------
// QCNN forward, split kernels:
//   expm -> layer0 gates (2 LDS passes, 3-gate register phases, 512-thr
//   blocks for 16 waves/CU) -> pool0 + layer1 gates + pooled outer products
//   -> reduce partials -> tail (layers 2..4 + measure).
// Bit convention: qubit q <-> address bit (19-q).  Gate digit r = 2*b(pa)+b(pb).
// pool LDS layout: w[t_lo*1056 + s*33 + u]  (odd stride 33).
// ---------------------------------------------------------------------------

__device__ __forceinline__ float2 cmul(float2 a, float2 b) {
  return make_float2(a.x * b.x - a.y * b.y, a.x * b.y + a.y * b.x);
}
__device__ __forceinline__ float2 cmadd(float2 acc, float2 a, float2 b) {
  acc.x = fmaf(a.x, b.x, fmaf(-a.y, b.y, acc.x));
  acc.y = fmaf(a.x, b.y, fmaf(a.y, b.x, acc.y));
  return acc;
}
// acc += a * conj(b)
__device__ __forceinline__ float2 cmaddc(float2 acc, float2 a, float2 b) {
  acc.x = fmaf(a.x, b.x, fmaf(a.y, b.y, acc.x));
  acc.y = fmaf(a.y, b.x, fmaf(-a.x, b.y, acc.y));
  return acc;
}
__device__ __forceinline__ int pad(int e) { return e + (e >> 4); }

__device__ __forceinline__ unsigned spread(unsigned v) {  // bit j -> 2j
  v = (v | (v << 8)) & 0x00FF00FFu;
  v = (v | (v << 4)) & 0x0F0F0F0Fu;
  v = (v | (v << 2)) & 0x33333333u;
  v = (v | (v << 1)) & 0x55555555u;
  return v;
}
__device__ __forceinline__ unsigned spread2(unsigned v) { return spread(spread(v)); }
__device__ __forceinline__ int ins(int x, int p) {  // insert zero bit at p
  return ((x >> p) << (p + 1)) | (x & ((1 << p) - 1));
}

__device__ __forceinline__ void gate4(float2& v0, float2& v1, float2& v2, float2& v3,
                                      const float2 (&U)[16]) {
  float2 n0 = cmul(U[0], v0);  n0 = cmadd(n0, U[1], v1);  n0 = cmadd(n0, U[2], v2);  n0 = cmadd(n0, U[3], v3);
  float2 n1 = cmul(U[4], v0);  n1 = cmadd(n1, U[5], v1);  n1 = cmadd(n1, U[6], v2);  n1 = cmadd(n1, U[7], v3);
  float2 n2 = cmul(U[8], v0);  n2 = cmadd(n2, U[9], v1);  n2 = cmadd(n2, U[10], v2); n2 = cmadd(n2, U[11], v3);
  float2 n3 = cmul(U[12], v0); n3 = cmadd(n3, U[13], v1); n3 = cmadd(n3, U[14], v2); n3 = cmadd(n3, U[15], v3);
  v0 = n0; v1 = n1; v2 = n2; v3 = n3;
}

// NG gates on a 16-elem register block (v index bit k <-> local bit k):
// (l1,l0), (l3,l2), and if NG==3 the sandwiched odd gate (l2,l1).
template <int NG>
__device__ __forceinline__ void gate16n(float2 (&v)[16], const float2 (&U)[16]) {
#pragma unroll
  for (int g = 0; g < 4; g++)
    gate4(v[g * 4 + 0], v[g * 4 + 1], v[g * 4 + 2], v[g * 4 + 3], U);
#pragma unroll
  for (int lo = 0; lo < 4; lo++)
    gate4(v[lo], v[lo + 4], v[lo + 8], v[lo + 12], U);
  if (NG == 3) {
#pragma unroll
    for (int b3 = 0; b3 < 2; b3++)
#pragma unroll
      for (int b0 = 0; b0 < 2; b0++) {
        int j = b3 * 8 + b0;
        gate4(v[j], v[j + 2], v[j + 4], v[j + 6], U);
      }
  }
}

// single 2-qubit gate (pa,pb) over padded 2^13 LDS tile (512 threads)
__device__ __forceinline__ void apply_gate_tile13(float2* t, const float2 (&U)[16],
                                                  int pa, int pb, int tid) {
  int p0 = pa < pb ? pa : pb;
  int p1 = pa < pb ? pb : pa;
  int m0 = (1 << p0) - 1, m1 = (1 << p1) - 1;
  int ia = 1 << pa, ib = 1 << pb;
#pragma unroll
  for (int g = tid; g < 2048; g += 512) {
    int idx = ((g & ~m0) << 1) | (g & m0);
    idx = ((idx & ~m1) << 1) | (idx & m1);
    int e0 = pad(idx), e1 = pad(idx | ib), e2 = pad(idx | ia), e3 = pad(idx | ia | ib);
    float2 v0 = t[e0], v1 = t[e1], v2 = t[e2], v3 = t[e3];
    gate4(v0, v1, v2, v3, U);
    t[e0] = v0; t[e1] = v1; t[e2] = v2; t[e3] = v3;
  }
}

// register phase over tile bits {p0<p1<p2<p3}: gates (p1,p0),(p3,p2)[,(p2,p1)]
// 512 threads: one 16-group per thread
template <int NG>
__device__ __forceinline__ void phase4_l0(float2* t, const float2 (&U)[16],
                                          int p0, int p1, int p2, int p3, int tid) {
  int o0 = 1 << p0, o1 = 1 << p1, o2 = 1 << p2, o3 = 1 << p3;
  int idx = ins(ins(ins(ins(tid, p0), p1), p2), p3);
  float2 v[16];
#pragma unroll
  for (int j = 0; j < 16; j++) {
    int off = ((j & 1) ? o0 : 0) + ((j & 2) ? o1 : 0) + ((j & 4) ? o2 : 0) + ((j & 8) ? o3 : 0);
    v[j] = t[pad(idx + off)];
  }
  gate16n<NG>(v, U);
#pragma unroll
  for (int j = 0; j < 16; j++) {
    int off = ((j & 1) ? o0 : 0) + ((j & 2) ? o1 : 0) + ((j & 4) ? o2 : 0) + ((j & 8) ? o3 : 0);
    t[pad(idx + off)] = v[j];
  }
}

// pool register phase: removes u-bits {a_lo<a_hi}, s-bits {c_lo<c_hi};
// o0..o3 = flat strides of local bits 0..3 (512 threads: one group each)
template <int NG>
__device__ __forceinline__ void phase4_pool(float2* w, const float2 (&U)[16],
                                            int a_lo, int a_hi, int c_lo, int c_hi,
                                            int o0, int o1, int o2, int o3, int tid) {
  int uu = tid & 7, ss = (tid >> 3) & 7, t_lo = tid >> 6;
  int u = ins(ins(uu, a_lo), a_hi);
  int s = ins(ins(ss, c_lo), c_hi);
  int base = t_lo * 1056 + s * 33 + u;
  float2 v[16];
#pragma unroll
  for (int j = 0; j < 16; j++) {
    int off = ((j & 1) ? o0 : 0) + ((j & 2) ? o1 : 0) + ((j & 4) ? o2 : 0) + ((j & 8) ? o3 : 0);
    v[j] = w[base + off];
  }
  gate16n<NG>(v, U);
#pragma unroll
  for (int j = 0; j < 16; j++) {
    int off = ((j & 1) ? o0 : 0) + ((j & 2) ? o1 : 0) + ((j & 4) ? o2 : 0) + ((j & 8) ? o3 : 0);
    w[base + off] = v[j];
  }
}

// pool P3: gates {1,0} then {2,1} on locals [o0=1(u0=i0), o1=33(s0=i1), o2=2(u1=i2)]
__device__ __forceinline__ void pool_p3(float2* w, const float2 (&U)[16], int tid) {
#pragma unroll
  for (int it = 0; it < 2; it++) {
    int h = tid + it * 512;
    int uu = h & 7, ss = (h >> 3) & 15, t_lo = h >> 7;
    int base = t_lo * 1056 + (ss << 1) * 33 + (uu << 2);
    float2 v[8];
    v[0] = w[base];      v[1] = w[base + 1];
    v[4] = w[base + 2];  v[5] = w[base + 3];
    v[2] = w[base + 33]; v[3] = w[base + 34];
    v[6] = w[base + 35]; v[7] = w[base + 36];
    gate4(v[0], v[1], v[2], v[3], U);   // {1,0}, u1=0
    gate4(v[4], v[5], v[6], v[7], U);   // {1,0}, u1=1
    gate4(v[0], v[2], v[4], v[6], U);   // {2,1}, u0=0
    gate4(v[1], v[3], v[5], v[7], U);   // {2,1}, u0=1
    w[base] = v[0];      w[base + 1] = v[1];
    w[base + 2] = v[4];  w[base + 3] = v[5];
    w[base + 33] = v[2]; w[base + 34] = v[3];
    w[base + 35] = v[6]; w[base + 36] = v[7];
  }
}

// ---------------------------------------------------------------------------
// Kernel A: U[l] = expm(A - A^H), fp64, lane-parallel (16 lanes per matrix)
// ---------------------------------------------------------------------------
__global__ __launch_bounds__(320) void expm_kernel(const float* __restrict__ Hre,
                                                   const float* __restrict__ Him,
                                                   float2* __restrict__ Uout) {
  int wave = threadIdx.x >> 6;
  int lane = threadIdx.x & 63;
  if (wave >= 5 || lane >= 16) return;
  int l = wave;
  int r = lane >> 2, c = lane & 3;
  double tr = (double)Hre[l * 16 + r * 4 + c] - (double)Hre[l * 16 + c * 4 + r];
  double ti = (double)Him[l * 16 + r * 4 + c] + (double)Him[l * 16 + c * 4 + r];
  double a = sqrt(tr * tr + ti * ti);
  a += __shfl_xor(a, 1, 64);
  a += __shfl_xor(a, 2, 64);
  double nrm = fmax(a, __shfl_xor(a, 4, 64));
  nrm = fmax(nrm, __shfl_xor(nrm, 8, 64));
  int s = 0;
  while (nrm > 0.25 && s < 60) { nrm *= 0.5; s++; }
  double sc = ldexp(1.0, -s);
  tr *= sc; ti *= sc;
  double id = (r == c) ? 1.0 : 0.0;
  double er = id, ei = 0.0, pr = id, pi = 0.0;
  for (int k = 1; k <= 16; k++) {
    double qr = 0.0, qi = 0.0;
#pragma unroll
    for (int m = 0; m < 4; m++) {
      double pmr = __shfl(pr, r * 4 + m, 64);
      double pmi = __shfl(pi, r * 4 + m, 64);
      double tmr = __shfl(tr, m * 4 + c, 64);
      double tmi = __shfl(ti, m * 4 + c, 64);
      qr = fma(pmr, tmr, fma(-pmi, tmi, qr));
      qi = fma(pmr, tmi, fma(pmi, tmr, qi));
    }
    double inv = 1.0 / (double)k;
    pr = qr * inv; pi = qi * inv;
    er += pr; ei += pi;
  }
  for (int it = 0; it < s; it++) {
    double qr = 0.0, qi = 0.0;
#pragma unroll
    for (int m = 0; m < 4; m++) {
      double amr = __shfl(er, r * 4 + m, 64);
      double ami = __shfl(ei, r * 4 + m, 64);
      double bmr = __shfl(er, m * 4 + c, 64);
      double bmi = __shfl(ei, m * 4 + c, 64);
      qr = fma(amr, bmr, fma(-ami, bmi, qr));
      qi = fma(amr, bmi, fma(ami, bmr, qi));
    }
    er = qr; ei = qi;
  }
  Uout[l * 16 + lane] = make_float2((float)er, (float)ei);
}

// ---------------------------------------------------------------------------
// Kernel B: layer-0 pass 1. Tile = addr bits 0..12; 11 gates in 4 round-trips.
// 512 threads/block -> 16 waves/CU.
// ---------------------------------------------------------------------------
__global__ __launch_bounds__(512, 4) void l0_pass1(const float* __restrict__ pre,
                                                   const float* __restrict__ pim,
                                                   const float2* __restrict__ Umat,
                                                   float2* __restrict__ state) {
  extern __shared__ float2 tile[];
  int tid = threadIdx.x;
  int bid = blockIdx.x;
  int b = bid >> 7, hi = bid & 127;
  size_t base = ((size_t)b << 20) | ((size_t)hi << 13);
  float2 U[16];
#pragma unroll
  for (int k = 0; k < 16; k++) U[k] = Umat[k];
  for (int e = tid; e < 8192; e += 512)
    tile[pad(e)] = make_float2(pre[base + e], pim[base + e]);
  __syncthreads();
  phase4_l0<3>(tile, U, 0, 1, 2, 3, tid);   __syncthreads(); // {1,0},{3,2},{2,1}
  phase4_l0<3>(tile, U, 4, 5, 6, 7, tid);   __syncthreads(); // {5,4},{7,6},{6,5}
  phase4_l0<3>(tile, U, 8, 9, 10, 11, tid); __syncthreads(); // {9,8},{11,10},{10,9}
  phase4_l0<2>(tile, U, 3, 4, 7, 8, tid);   __syncthreads(); // {4,3},{8,7}
  for (int e = tid; e < 8192; e += 512) state[base + e] = tile[pad(e)];
}

// ---------------------------------------------------------------------------
// Kernel C: layer-0 pass 2. Tile = bits {0..3} U {11..19}; 9 gates in 4 RTs.
// ---------------------------------------------------------------------------
__global__ __launch_bounds__(512, 4) void l0_pass2(const float2* __restrict__ Umat,
                                                   float2* __restrict__ state) {
  extern __shared__ float2 tile[];
  int tid = threadIdx.x;
  int bid = blockIdx.x;
  int b = bid >> 7, mid = bid & 127;
  size_t base = ((size_t)b << 20) | ((size_t)mid << 4);
  float2 U[16];
#pragma unroll
  for (int k = 0; k < 16; k++) U[k] = Umat[k];
  for (int e = tid; e < 8192; e += 512) {
    size_t a = base + (((size_t)(e >> 4)) << 11) + (size_t)(e & 15);
    tile[pad(e)] = state[a];
  }
  __syncthreads();
  phase4_l0<3>(tile, U, 5, 6, 7, 8, tid);    __syncthreads(); // {6,5},{8,7},{7,6}
  phase4_l0<3>(tile, U, 9, 10, 11, 12, tid); __syncthreads(); // {10,9},{12,11},{11,10}
  phase4_l0<2>(tile, U, 4, 5, 8, 9, tid);    __syncthreads(); // {5,4},{9,8}
  apply_gate_tile13(tile, U, 0, 12, tid);    __syncthreads(); // wrap {0,12}
  for (int e = tid; e < 8192; e += 512) {
    size_t a = base + (((size_t)(e >> 4)) << 11) + (size_t)(e & 15);
    state[a] = tile[pad(e)];
  }
}

// ---------------------------------------------------------------------------
// Kernel D: pool0 + layer1 gates (4 RTs) + pool1 partials. 512 threads.
// ---------------------------------------------------------------------------
__global__ __launch_bounds__(512, 4) void pool_l1(const float2* __restrict__ Umat,
                                                  const float2* __restrict__ state,
                                                  float2* __restrict__ partial) {
  extern __shared__ float2 w[];  // 8448 float2
  int tid = threadIdx.x;
  int bid = blockIdx.x;
  int b = bid >> 7, thi = bid & 127;
  size_t bbase = (size_t)b << 20;
  float2 U[16];
#pragma unroll
  for (int k = 0; k < 16; k++) U[k] = Umat[16 + k];
  unsigned tbase = spread((unsigned)(thi << 3)) << 1;
  for (int e = tid; e < 8192; e += 512) {
    int u = e & 31, s = (e >> 5) & 31, t_lo = e >> 10;
    unsigned addr = tbase | (spread((unsigned)t_lo) << 1) | spread2((unsigned)u)
                  | (spread2((unsigned)s) << 2);
    w[t_lo * 1056 + s * 33 + u] = state[bbase + (size_t)addr];
  }
  __syncthreads();
  // i-bit even 2j = u-bit j (stride 2^j); i-bit odd 2j+1 = s-bit j (stride 33*2^j)
  phase4_pool<3>(w, U, 3, 4, 3, 4, 8, 264, 16, 528, tid); __syncthreads(); // {7,6},{9,8},{8,7}
  phase4_pool<3>(w, U, 1, 2, 1, 2, 2, 66, 4, 132, tid);   __syncthreads(); // {3,2},{5,4},{4,3}
  pool_p3(w, U, tid);                                     __syncthreads(); // {1,0},{2,1}
  phase4_pool<2>(w, U, 0, 3, 2, 4, 132, 8, 528, 1, tid);  __syncthreads(); // {6,5},{0,9}
  // pool1: rho2[u,v] = sum_{t,s} w[t,s,u]*conj(w[t,s,v]); 4x4 per lane,
  // 8 waves: wave wv handles t_lo = wv
  int wv = tid >> 6, lane = tid & 63;
  int u0 = (lane >> 3) << 2, v0 = (lane & 7) << 2;
  float2 acc[4][4];
#pragma unroll
  for (int i = 0; i < 4; i++)
#pragma unroll
    for (int j = 0; j < 4; j++) acc[i][j] = make_float2(0.f, 0.f);
  {
    int tb = wv * 1056;
#pragma unroll 4
    for (int s = 0; s < 32; s++) {
      int row = tb + s * 33;
      float2 x[4], y[4];
#pragma unroll
      for (int i = 0; i < 4; i++) { x[i] = w[row + u0 + i]; y[i] = w[row + v0 + i]; }
#pragma unroll
      for (int i = 0; i < 4; i++)
#pragma unroll
        for (int j = 0; j < 4; j++) acc[i][j] = cmaddc(acc[i][j], x[i], y[j]);
    }
  }
  __syncthreads();  // w dead; reuse for cross-wave reduce
  if (wv > 0) {
#pragma unroll
    for (int i = 0; i < 4; i++)
#pragma unroll
      for (int j = 0; j < 4; j++)
        w[(wv - 1) * 1024 + (u0 + i) * 32 + (v0 + j)] = acc[i][j];
  }
  __syncthreads();
  if (wv == 0) {
    float2* outp = partial + ((size_t)bid << 10);
#pragma unroll
    for (int i = 0; i < 4; i++)
#pragma unroll
      for (int j = 0; j < 4; j++) {
        float2 a = acc[i][j];
#pragma unroll
        for (int k = 0; k < 7; k++) {
          float2 o = w[k * 1024 + (u0 + i) * 32 + (v0 + j)];
          a.x += o.x; a.y += o.y;
        }
        outp[(u0 + i) * 32 + (v0 + j)] = a;
      }
  }
}

// ---------------------------------------------------------------------------
// Kernel E: reduce 128 partials per batch -> rho32 (8192 floats)
// ---------------------------------------------------------------------------
__global__ __launch_bounds__(256) void reduce_partials(const float* __restrict__ partial,
                                                       float* __restrict__ rho32) {
  int idx = blockIdx.x * 256 + threadIdx.x;  // 0..8191
  int b = idx >> 11, p = idx & 2047;
  float acc = 0.f;
#pragma unroll 4
  for (int h = 0; h < 128; h++) acc += partial[(((size_t)(b * 128 + h)) << 11) + (size_t)p];
  rho32[idx] = acc;
}

// ---------------------------------------------------------------------------
// Kernel F: layers 2..4 (32x32 -> 2x2 dm) + measure. One block per batch.
// ---------------------------------------------------------------------------
__global__ __launch_bounds__(256) void finish(const float2* __restrict__ Umat,
                                              const float2* __restrict__ rho32,
                                              float* __restrict__ out) {
  __shared__ float2 rho[1024];
  __shared__ float2 r3s[64];
  __shared__ float2 r4s[16];
  int tid = threadIdx.x;
  int b = blockIdx.x;
  for (int p = tid; p < 1024; p += 256) rho[p] = rho32[(b << 10) + p];
  __syncthreads();

  float2 U[16], Uc[16];
#pragma unroll
  for (int k = 0; k < 16; k++) { U[k] = Umat[32 + k]; Uc[k] = make_float2(U[k].x, -U[k].y); }
  const int gl2[4][2] = {{4,3},{2,1},{3,2},{1,0}};
#pragma unroll
  for (int gi = 0; gi < 4; gi++) {
    int pa = gl2[gi][0], pb = gl2[gi][1];
    int p0 = pa < pb ? pa : pb, p1 = pa < pb ? pb : pa;
    int m0 = (1 << p0) - 1, m1 = (1 << p1) - 1;
    int ia = 1 << pa, ib = 1 << pb;
    {
      int j = tid >> 3, g = tid & 7;
      int idx = ((g & ~m0) << 1) | (g & m0);
      idx = ((idx & ~m1) << 1) | (idx & m1);
      float2 v0 = rho[idx * 32 + j], v1 = rho[(idx | ib) * 32 + j];
      float2 v2 = rho[(idx | ia) * 32 + j], v3 = rho[(idx | ia | ib) * 32 + j];
      gate4(v0, v1, v2, v3, U);
      rho[idx * 32 + j] = v0; rho[(idx | ib) * 32 + j] = v1;
      rho[(idx | ia) * 32 + j] = v2; rho[(idx | ia | ib) * 32 + j] = v3;
    }
    __syncthreads();
    {
      int i = tid >> 3, g = tid & 7;
      int idx = ((g & ~m0) << 1) | (g & m0);
      idx = ((idx & ~m1) << 1) | (idx & m1);
      float2 v0 = rho[i * 32 + idx], v1 = rho[i * 32 + (idx | ib)];
      float2 v2 = rho[i * 32 + (idx | ia)], v3 = rho[i * 32 + (idx | ia | ib)];
      gate4(v0, v1, v2, v3, Uc);
      rho[i * 32 + idx] = v0; rho[i * 32 + (idx | ib)] = v1;
      rho[i * 32 + (idx | ia)] = v2; rho[i * 32 + (idx | ia | ib)] = v3;
    }
    __syncthreads();
  }
  if (tid < 64) {
    int u = tid >> 3, v = tid & 7;
    float2 acc = {0.f, 0.f};
#pragma unroll
    for (int s = 0; s < 4; s++) {
      int iu = ((s >> 1) << 4) | ((u >> 2) << 3) | ((s & 1) << 2) | (((u >> 1) & 1) << 1) | (u & 1);
      int iv = ((s >> 1) << 4) | ((v >> 2) << 3) | ((s & 1) << 2) | (((v >> 1) & 1) << 1) | (v & 1);
      float2 x = rho[iu * 32 + iv];
      acc.x += x.x; acc.y += x.y;
    }
    r3s[u * 8 + v] = acc;
  }
  __syncthreads();

#pragma unroll
  for (int k = 0; k < 16; k++) { U[k] = Umat[48 + k]; Uc[k] = make_float2(U[k].x, -U[k].y); }
  const int gl3[2][2] = {{2,1},{1,0}};
#pragma unroll
  for (int gi = 0; gi < 2; gi++) {
    int pa = gl3[gi][0], pb = gl3[gi][1];
    int p0 = pa < pb ? pa : pb, p1 = pa < pb ? pb : pa;
    int m0 = (1 << p0) - 1, m1 = (1 << p1) - 1;
    int ia = 1 << pa, ib = 1 << pb;
    if (tid < 16) {
      int j = tid >> 1, g = tid & 1;
      int idx = ((g & ~m0) << 1) | (g & m0);
      idx = ((idx & ~m1) << 1) | (idx & m1);
      float2 v0 = r3s[idx * 8 + j], v1 = r3s[(idx | ib) * 8 + j];
      float2 v2 = r3s[(idx | ia) * 8 + j], v3 = r3s[(idx | ia | ib) * 8 + j];
      gate4(v0, v1, v2, v3, U);
      r3s[idx * 8 + j] = v0; r3s[(idx | ib) * 8 + j] = v1;
      r3s[(idx | ia) * 8 + j] = v2; r3s[(idx | ia | ib) * 8 + j] = v3;
    }
    __syncthreads();
    if (tid < 16) {
      int i = tid >> 1, g = tid & 1;
      int idx = ((g & ~m0) << 1) | (g & m0);
      idx = ((idx & ~m1) << 1) | (idx & m1);
      float2 v0 = r3s[i * 8 + idx], v1 = r3s[i * 8 + (idx | ib)];
      float2 v2 = r3s[i * 8 + (idx | ia)], v3 = r3s[i * 8 + (idx | ia | ib)];
      gate4(v0, v1, v2, v3, Uc);
      r3s[i * 8 + idx] = v0; r3s[i * 8 + (idx | ib)] = v1;
      r3s[i * 8 + (idx | ia)] = v2; r3s[i * 8 + (idx | ia | ib)] = v3;
    }
    __syncthreads();
  }
  if (tid < 16) {
    int u = tid >> 2, v = tid & 3;
    float2 acc = {0.f, 0.f};
#pragma unroll
    for (int s = 0; s < 2; s++) {
      float2 x = r3s[((s << 2) | u) * 8 + ((s << 2) | v)];
      acc.x += x.x; acc.y += x.y;
    }
    r4s[u * 4 + v] = acc;
  }
  __syncthreads();

#pragma unroll
  for (int k = 0; k < 16; k++) { U[k] = Umat[64 + k]; Uc[k] = make_float2(U[k].x, -U[k].y); }
  if (tid < 4) {
    int j = tid;
    float2 v0 = r4s[0 * 4 + j], v1 = r4s[1 * 4 + j], v2 = r4s[2 * 4 + j], v3 = r4s[3 * 4 + j];
    gate4(v0, v1, v2, v3, U);
    r4s[0 * 4 + j] = v0; r4s[1 * 4 + j] = v1; r4s[2 * 4 + j] = v2; r4s[3 * 4 + j] = v3;
  }
  __syncthreads();
  if (tid < 4) {
    int i = tid;
    float2 v0 = r4s[i * 4 + 0], v1 = r4s[i * 4 + 1], v2 = r4s[i * 4 + 2], v3 = r4s[i * 4 + 3];
    gate4(v0, v1, v2, v3, Uc);
    r4s[i * 4 + 0] = v0; r4s[i * 4 + 1] = v1; r4s[i * 4 + 2] = v2; r4s[i * 4 + 3] = v3;
  }
  __syncthreads();
  if (tid == 0) out[b] = r4s[0].x + r4s[10].x;
}

// ---------------------------------------------------------------------------
extern "C" void kernel_launch(void* const* d_in, const int* in_sizes, int n_in,
                              void* d_out, int out_size, void* d_ws, size_t ws_size,
                              hipStream_t stream) {
  const float* psi_re = (const float*)d_in[0];
  const float* psi_im = (const float*)d_in[1];
  const float* H_re = (const float*)d_in[2];
  const float* H_im = (const float*)d_in[3];
  float* out = (float*)d_out;

  char* ws = (char*)d_ws;
  float2* Umat = (float2*)ws;                                   // 5*16 float2
  float2* state = (float2*)(ws + 4096);                         // 32 MB
  float* partial = (float*)(ws + 4096 + ((size_t)1 << 25));     // 4 MB
  float* rho32 = (float*)(ws + 4096 + ((size_t)1 << 25) + ((size_t)1 << 22));  // 32 KB

  const size_t LDS_L0 = 8704 * sizeof(float2);    // padded 8192
  const size_t LDS_POOL = 8448 * sizeof(float2);  // 8*1056 stride-33 rows

  hipLaunchKernelGGL(expm_kernel, dim3(1), dim3(320), 0, stream, H_re, H_im, Umat);
  hipLaunchKernelGGL(l0_pass1, dim3(512), dim3(512), LDS_L0, stream,
                     psi_re, psi_im, Umat, state);
  hipLaunchKernelGGL(l0_pass2, dim3(512), dim3(512), LDS_L0, stream, Umat, state);
  hipLaunchKernelGGL(pool_l1, dim3(512), dim3(512), LDS_POOL, stream,
                     Umat, state, (float2*)partial);
  hipLaunchKernelGGL(reduce_partials, dim3(32), dim3(256), 0, stream, partial, rho32);
  hipLaunchKernelGGL(finish, dim3(4), dim3(256), 0, stream, Umat, (const float2*)rho32, out);
}

// Round 7
// 183.888 us; speedup vs baseline: 1.2858x; 1.0304x over previous
//
#include <hip/hip_runtime.h>
#include <math.h>

// ---------------------------------------------------------------------------
// QCNN forward, split kernels (expm folded into l0_pass1; float4 global I/O):
//   l0_pass1 (computes U inline, block0 publishes Umat) -> l0_pass2 ->
//   pool0 + layer1 gates + pooled outer products -> reduce -> tail.
// Bit convention: qubit q <-> address bit (19-q).  Gate digit r = 2*b(pa)+b(pb).
// pool LDS layout: w[t_lo*1120 + s*35 + u]  (odd stride 35; (3s+u)%16 banks).
// ---------------------------------------------------------------------------

__device__ __forceinline__ float2 cmul(float2 a, float2 b) {
  return make_float2(a.x * b.x - a.y * b.y, a.x * b.y + a.y * b.x);
}
__device__ __forceinline__ float2 cmadd(float2 acc, float2 a, float2 b) {
  acc.x = fmaf(a.x, b.x, fmaf(-a.y, b.y, acc.x));
  acc.y = fmaf(a.x, b.y, fmaf(a.y, b.x, acc.y));
  return acc;
}
// acc += a * conj(b)
__device__ __forceinline__ float2 cmaddc(float2 acc, float2 a, float2 b) {
  acc.x = fmaf(a.x, b.x, fmaf(a.y, b.y, acc.x));
  acc.y = fmaf(a.y, b.x, fmaf(-a.x, b.y, acc.y));
  return acc;
}
__device__ __forceinline__ int pad(int e) { return e + (e >> 4); }

__device__ __forceinline__ unsigned spread(unsigned v) {  // bit j -> 2j
  v = (v | (v << 8)) & 0x00FF00FFu;
  v = (v | (v << 4)) & 0x0F0F0F0Fu;
  v = (v | (v << 2)) & 0x33333333u;
  v = (v | (v << 1)) & 0x55555555u;
  return v;
}
__device__ __forceinline__ unsigned spread2(unsigned v) { return spread(spread(v)); }
__device__ __forceinline__ int ins(int x, int p) {  // insert zero bit at p
  return ((x >> p) << (p + 1)) | (x & ((1 << p) - 1));
}

__device__ __forceinline__ void gate4(float2& v0, float2& v1, float2& v2, float2& v3,
                                      const float2 (&U)[16]) {
  float2 n0 = cmul(U[0], v0);  n0 = cmadd(n0, U[1], v1);  n0 = cmadd(n0, U[2], v2);  n0 = cmadd(n0, U[3], v3);
  float2 n1 = cmul(U[4], v0);  n1 = cmadd(n1, U[5], v1);  n1 = cmadd(n1, U[6], v2);  n1 = cmadd(n1, U[7], v3);
  float2 n2 = cmul(U[8], v0);  n2 = cmadd(n2, U[9], v1);  n2 = cmadd(n2, U[10], v2); n2 = cmadd(n2, U[11], v3);
  float2 n3 = cmul(U[12], v0); n3 = cmadd(n3, U[13], v1); n3 = cmadd(n3, U[14], v2); n3 = cmadd(n3, U[15], v3);
  v0 = n0; v1 = n1; v2 = n2; v3 = n3;
}

// NG gates on a 16-elem register block: (l1,l0), (l3,l2), [+(l2,l1) if NG==3]
template <int NG>
__device__ __forceinline__ void gate16n(float2 (&v)[16], const float2 (&U)[16]) {
#pragma unroll
  for (int g = 0; g < 4; g++)
    gate4(v[g * 4 + 0], v[g * 4 + 1], v[g * 4 + 2], v[g * 4 + 3], U);
#pragma unroll
  for (int lo = 0; lo < 4; lo++)
    gate4(v[lo], v[lo + 4], v[lo + 8], v[lo + 12], U);
  if (NG == 3) {
#pragma unroll
    for (int b3 = 0; b3 < 2; b3++)
#pragma unroll
      for (int b0 = 0; b0 < 2; b0++) {
        int j = b3 * 8 + b0;
        gate4(v[j], v[j + 2], v[j + 4], v[j + 6], U);
      }
  }
}

// single 2-qubit gate (pa,pb) over padded 2^13 LDS tile (512 threads)
__device__ __forceinline__ void apply_gate_tile13(float2* t, const float2 (&U)[16],
                                                  int pa, int pb, int tid) {
  int p0 = pa < pb ? pa : pb;
  int p1 = pa < pb ? pb : pa;
  int m0 = (1 << p0) - 1, m1 = (1 << p1) - 1;
  int ia = 1 << pa, ib = 1 << pb;
#pragma unroll
  for (int g = tid; g < 2048; g += 512) {
    int idx = ((g & ~m0) << 1) | (g & m0);
    idx = ((idx & ~m1) << 1) | (idx & m1);
    int e0 = pad(idx), e1 = pad(idx | ib), e2 = pad(idx | ia), e3 = pad(idx | ia | ib);
    float2 v0 = t[e0], v1 = t[e1], v2 = t[e2], v3 = t[e3];
    gate4(v0, v1, v2, v3, U);
    t[e0] = v0; t[e1] = v1; t[e2] = v2; t[e3] = v3;
  }
}

// register phase over tile bits {p0<p1<p2<p3}: gates (p1,p0),(p3,p2)[,(p2,p1)]
template <int NG>
__device__ __forceinline__ void phase4_l0(float2* t, const float2 (&U)[16],
                                          int p0, int p1, int p2, int p3, int tid) {
  int o0 = 1 << p0, o1 = 1 << p1, o2 = 1 << p2, o3 = 1 << p3;
  int idx = ins(ins(ins(ins(tid, p0), p1), p2), p3);
  float2 v[16];
#pragma unroll
  for (int j = 0; j < 16; j++) {
    int off = ((j & 1) ? o0 : 0) + ((j & 2) ? o1 : 0) + ((j & 4) ? o2 : 0) + ((j & 8) ? o3 : 0);
    v[j] = t[pad(idx + off)];
  }
  gate16n<NG>(v, U);
#pragma unroll
  for (int j = 0; j < 16; j++) {
    int off = ((j & 1) ? o0 : 0) + ((j & 2) ? o1 : 0) + ((j & 4) ? o2 : 0) + ((j & 8) ? o3 : 0);
    t[pad(idx + off)] = v[j];
  }
}

// pool register phase: removes u-bits {a_lo<a_hi}, s-bits {c_lo<c_hi};
// o0..o3 = flat strides of local bits 0..3 (512 threads: one group each)
template <int NG>
__device__ __forceinline__ void phase4_pool(float2* w, const float2 (&U)[16],
                                            int a_lo, int a_hi, int c_lo, int c_hi,
                                            int o0, int o1, int o2, int o3, int tid) {
  int uu = tid & 7, ss = (tid >> 3) & 7, t_lo = tid >> 6;
  int u = ins(ins(uu, a_lo), a_hi);
  int s = ins(ins(ss, c_lo), c_hi);
  int base = t_lo * 1120 + s * 35 + u;
  float2 v[16];
#pragma unroll
  for (int j = 0; j < 16; j++) {
    int off = ((j & 1) ? o0 : 0) + ((j & 2) ? o1 : 0) + ((j & 4) ? o2 : 0) + ((j & 8) ? o3 : 0);
    v[j] = w[base + off];
  }
  gate16n<NG>(v, U);
#pragma unroll
  for (int j = 0; j < 16; j++) {
    int off = ((j & 1) ? o0 : 0) + ((j & 2) ? o1 : 0) + ((j & 4) ? o2 : 0) + ((j & 8) ? o3 : 0);
    w[base + off] = v[j];
  }
}

// pool P3: gates {1,0} then {2,1} on locals [o0=1(u0=i0), o1=35(s0=i1), o2=2(u1=i2)]
__device__ __forceinline__ void pool_p3(float2* w, const float2 (&U)[16], int tid) {
#pragma unroll
  for (int it = 0; it < 2; it++) {
    int h = tid + it * 512;
    int uu = h & 7, ss = (h >> 3) & 15, t_lo = h >> 7;
    int base = t_lo * 1120 + (ss << 1) * 35 + (uu << 2);
    float2 v[8];
    v[0] = w[base];      v[1] = w[base + 1];
    v[4] = w[base + 2];  v[5] = w[base + 3];
    v[2] = w[base + 35]; v[3] = w[base + 36];
    v[6] = w[base + 37]; v[7] = w[base + 38];
    gate4(v[0], v[1], v[2], v[3], U);   // {1,0}, u1=0
    gate4(v[4], v[5], v[6], v[7], U);   // {1,0}, u1=1
    gate4(v[0], v[2], v[4], v[6], U);   // {2,1}, u0=0
    gate4(v[1], v[3], v[5], v[7], U);   // {2,1}, u0=1
    w[base] = v[0];      w[base + 1] = v[1];
    w[base + 2] = v[4];  w[base + 3] = v[5];
    w[base + 35] = v[2]; w[base + 36] = v[3];
    w[base + 37] = v[6]; w[base + 38] = v[7];
  }
}

// 16-lane expm(A - A^H) in fp64, width-16 shuffles. Lane l16 holds element
// (r,c) = (l16>>2, l16&3). Returns U[l] element as float2.
__device__ __forceinline__ float2 expm16(const float* __restrict__ Hre,
                                         const float* __restrict__ Him,
                                         int l, int l16) {
  int r = l16 >> 2, c = l16 & 3;
  double tr = (double)Hre[l * 16 + r * 4 + c] - (double)Hre[l * 16 + c * 4 + r];
  double ti = (double)Him[l * 16 + r * 4 + c] + (double)Him[l * 16 + c * 4 + r];
  double a = sqrt(tr * tr + ti * ti);
  a += __shfl_xor(a, 1, 16);
  a += __shfl_xor(a, 2, 16);
  double nrm = fmax(a, __shfl_xor(a, 4, 16));
  nrm = fmax(nrm, __shfl_xor(nrm, 8, 16));
  int s = 0;
  while (nrm > 0.25 && s < 60) { nrm *= 0.5; s++; }
  double sc = ldexp(1.0, -s);
  tr *= sc; ti *= sc;
  double id = (r == c) ? 1.0 : 0.0;
  double er = id, ei = 0.0, pr = id, pi = 0.0;
  for (int k = 1; k <= 16; k++) {
    double qr = 0.0, qi = 0.0;
#pragma unroll
    for (int m = 0; m < 4; m++) {
      double pmr = __shfl(pr, r * 4 + m, 16);
      double pmi = __shfl(pi, r * 4 + m, 16);
      double tmr = __shfl(tr, m * 4 + c, 16);
      double tmi = __shfl(ti, m * 4 + c, 16);
      qr = fma(pmr, tmr, fma(-pmi, tmi, qr));
      qi = fma(pmr, tmi, fma(pmi, tmr, qi));
    }
    double inv = 1.0 / (double)k;
    pr = qr * inv; pi = qi * inv;
    er += pr; ei += pi;
  }
  for (int it = 0; it < s; it++) {
    double qr = 0.0, qi = 0.0;
#pragma unroll
    for (int m = 0; m < 4; m++) {
      double amr = __shfl(er, r * 4 + m, 16);
      double ami = __shfl(ei, r * 4 + m, 16);
      double bmr = __shfl(er, m * 4 + c, 16);
      double bmi = __shfl(ei, m * 4 + c, 16);
      qr = fma(amr, bmr, fma(-ami, bmi, qr));
      qi = fma(amr, bmi, fma(ami, bmr, qi));
    }
    er = qr; ei = qi;
  }
  return make_float2((float)er, (float)ei);
}

// ---------------------------------------------------------------------------
// Kernel B: layer-0 pass 1 + inline expm. Tile = addr bits 0..12; 11 gates in
// 4 round-trips. Every block computes U0 for itself; block 0 publishes all 5
// layers to Umat (global) for the downstream kernels.
// ---------------------------------------------------------------------------
__global__ __launch_bounds__(512, 4) void l0_pass1(const float* __restrict__ pre,
                                                   const float* __restrict__ pim,
                                                   const float* __restrict__ Hre,
                                                   const float* __restrict__ Him,
                                                   float2* __restrict__ Umat,
                                                   float2* __restrict__ state) {
  extern __shared__ float2 tile[];
  __shared__ float2 Ush[16];
  int tid = threadIdx.x;
  int bid = blockIdx.x;
  int b = bid >> 7, hi = bid & 127;
  size_t base = ((size_t)b << 20) | ((size_t)hi << 13);
  // tile load (float4; overlaps with expm below)
  for (int e4 = tid; e4 < 2048; e4 += 512) {
    int e = e4 << 2;
    float4 re = *(const float4*)&pre[base + e];
    float4 im = *(const float4*)&pim[base + e];
    int d = pad(e);
    tile[d] = make_float2(re.x, im.x);
    tile[d + 1] = make_float2(re.y, im.y);
    tile[d + 2] = make_float2(re.z, im.z);
    tile[d + 3] = make_float2(re.w, im.w);
  }
  // inline expm: wave0 groups 0..3 -> layers 0..3; wave1 group0 -> layer 4.
  // Non-block-0 only computes layer 0 (needed locally).
  {
    int wv = tid >> 6, g16 = (tid & 63) >> 4, l16 = tid & 15;
    int layer = (wv == 0) ? g16 : ((wv == 1 && g16 == 0) ? 4 : -1);
    if (layer == 0 || (bid == 0 && layer > 0)) {
      float2 ue = expm16(Hre, Him, layer, l16);
      if (layer == 0) Ush[l16] = ue;
      if (bid == 0) Umat[layer * 16 + l16] = ue;
    }
  }
  __syncthreads();
  float2 U[16];
#pragma unroll
  for (int k = 0; k < 16; k++) U[k] = Ush[k];
  phase4_l0<3>(tile, U, 0, 1, 2, 3, tid);   __syncthreads(); // {1,0},{3,2},{2,1}
  phase4_l0<3>(tile, U, 4, 5, 6, 7, tid);   __syncthreads(); // {5,4},{7,6},{6,5}
  phase4_l0<3>(tile, U, 8, 9, 10, 11, tid); __syncthreads(); // {9,8},{11,10},{10,9}
  phase4_l0<2>(tile, U, 3, 4, 7, 8, tid);   __syncthreads(); // {4,3},{8,7}
  for (int e4 = tid; e4 < 2048; e4 += 512) {
    int e = e4 << 2;
    int d = pad(e);
    float2 a = tile[d], b2 = tile[d + 1], c = tile[d + 2], d2 = tile[d + 3];
    float4* dst = (float4*)&state[base + e];
    dst[0] = make_float4(a.x, a.y, b2.x, b2.y);
    dst[1] = make_float4(c.x, c.y, d2.x, d2.y);
  }
}

// ---------------------------------------------------------------------------
// Kernel C: layer-0 pass 2. Tile = bits {0..3} U {11..19}; 9 gates in 4 RTs.
// ---------------------------------------------------------------------------
__global__ __launch_bounds__(512, 4) void l0_pass2(const float2* __restrict__ Umat,
                                                   float2* __restrict__ state) {
  extern __shared__ float2 tile[];
  int tid = threadIdx.x;
  int bid = blockIdx.x;
  int b = bid >> 7, mid = bid & 127;
  size_t base = ((size_t)b << 20) | ((size_t)mid << 4);
  float2 U[16];
#pragma unroll
  for (int k = 0; k < 16; k++) U[k] = Umat[k];
  // chunks of 16 elements at stride 2048; float4 = 2 complex
  for (int f = tid; f < 2048; f += 512) {
    int chunk = f >> 2, q = (f & 3) << 2;
    size_t a = base + ((size_t)chunk << 11) + q;
    const float4* src = (const float4*)&state[a];
    float4 v0 = src[0], v1 = src[1];
    int d = pad(chunk * 16 + q);
    tile[d] = make_float2(v0.x, v0.y);
    tile[d + 1] = make_float2(v0.z, v0.w);
    tile[d + 2] = make_float2(v1.x, v1.y);
    tile[d + 3] = make_float2(v1.z, v1.w);
  }
  __syncthreads();
  phase4_l0<3>(tile, U, 5, 6, 7, 8, tid);    __syncthreads(); // {6,5},{8,7},{7,6}
  phase4_l0<3>(tile, U, 9, 10, 11, 12, tid); __syncthreads(); // {10,9},{12,11},{11,10}
  phase4_l0<2>(tile, U, 4, 5, 8, 9, tid);    __syncthreads(); // {5,4},{9,8}
  apply_gate_tile13(tile, U, 0, 12, tid);    __syncthreads(); // wrap {0,12}
  for (int f = tid; f < 2048; f += 512) {
    int chunk = f >> 2, q = (f & 3) << 2;
    size_t a = base + ((size_t)chunk << 11) + q;
    int d = pad(chunk * 16 + q);
    float2 x0 = tile[d], x1 = tile[d + 1], x2 = tile[d + 2], x3 = tile[d + 3];
    float4* dst = (float4*)&state[a];
    dst[0] = make_float4(x0.x, x0.y, x1.x, x1.y);
    dst[1] = make_float4(x2.x, x2.y, x3.x, x3.y);
  }
}

// ---------------------------------------------------------------------------
// Kernel D: pool0 + layer1 gates (4 RTs) + pool1 partials. 512 threads.
// LDS w[t_lo*1120 + s*35 + u].
// ---------------------------------------------------------------------------
__global__ __launch_bounds__(512, 4) void pool_l1(const float2* __restrict__ Umat,
                                                  const float2* __restrict__ state,
                                                  float2* __restrict__ partial) {
  extern __shared__ float2 w[];  // 8960 float2
  int tid = threadIdx.x;
  int bid = blockIdx.x;
  int b = bid >> 7, thi = bid & 127;
  size_t bbase = (size_t)b << 20;
  float2 U[16];
#pragma unroll
  for (int k = 0; k < 16; k++) U[k] = Umat[16 + k];
  unsigned tbase = spread((unsigned)(thi << 3)) << 1;
  // gather: u-pairs are memory-adjacent (u0 <-> addr bit0) -> float4
  for (int f = tid; f < 4096; f += 512) {
    int up = f & 15, s = (f >> 4) & 31, t_lo = f >> 9;
    unsigned addr = tbase | (spread((unsigned)t_lo) << 1) | (spread2((unsigned)up) << 4)
                  | (spread2((unsigned)s) << 2);
    float4 v = *(const float4*)&state[bbase + (size_t)addr];
    int c = t_lo * 1120 + s * 35 + (up << 1);
    w[c] = make_float2(v.x, v.y);
    w[c + 1] = make_float2(v.z, v.w);
  }
  __syncthreads();
  // i-bit even 2j = u-bit j (stride 2^j); i-bit odd 2j+1 = s-bit j (stride 35*2^j)
  phase4_pool<3>(w, U, 3, 4, 3, 4, 8, 280, 16, 560, tid); __syncthreads(); // {7,6},{9,8},{8,7}
  phase4_pool<3>(w, U, 1, 2, 1, 2, 2, 70, 4, 140, tid);   __syncthreads(); // {3,2},{5,4},{4,3}
  pool_p3(w, U, tid);                                     __syncthreads(); // {1,0},{2,1}
  phase4_pool<2>(w, U, 0, 3, 2, 4, 140, 8, 560, 1, tid);  __syncthreads(); // {6,5},{0,9}
  // pool1: rho2[u,v] = sum_{t,s} w[t,s,u]*conj(w[t,s,v]); 4x4 per lane,
  // 8 waves: wave wv handles t_lo = wv
  int wv = tid >> 6, lane = tid & 63;
  int u0 = (lane >> 3) << 2, v0 = (lane & 7) << 2;
  float2 acc[4][4];
#pragma unroll
  for (int i = 0; i < 4; i++)
#pragma unroll
    for (int j = 0; j < 4; j++) acc[i][j] = make_float2(0.f, 0.f);
  {
    int tb = wv * 1120;
#pragma unroll 4
    for (int s = 0; s < 32; s++) {
      int row = tb + s * 35;
      float2 x[4], y[4];
#pragma unroll
      for (int i = 0; i < 4; i++) { x[i] = w[row + u0 + i]; y[i] = w[row + v0 + i]; }
#pragma unroll
      for (int i = 0; i < 4; i++)
#pragma unroll
        for (int j = 0; j < 4; j++) acc[i][j] = cmaddc(acc[i][j], x[i], y[j]);
    }
  }
  __syncthreads();  // w dead; reuse for cross-wave reduce
  if (wv > 0) {
#pragma unroll
    for (int i = 0; i < 4; i++)
#pragma unroll
      for (int j = 0; j < 4; j++)
        w[(wv - 1) * 1024 + (u0 + i) * 32 + (v0 + j)] = acc[i][j];
  }
  __syncthreads();
  if (wv == 0) {
    float2* outp = partial + ((size_t)bid << 10);
#pragma unroll
    for (int i = 0; i < 4; i++)
#pragma unroll
      for (int j = 0; j < 4; j++) {
        float2 a = acc[i][j];
#pragma unroll
        for (int k = 0; k < 7; k++) {
          float2 o = w[k * 1024 + (u0 + i) * 32 + (v0 + j)];
          a.x += o.x; a.y += o.y;
        }
        outp[(u0 + i) * 32 + (v0 + j)] = a;
      }
  }
}

// ---------------------------------------------------------------------------
// Kernel E: reduce 128 partials per batch -> rho32 (float4)
// ---------------------------------------------------------------------------
__global__ __launch_bounds__(256) void reduce_partials(const float4* __restrict__ partial,
                                                       float4* __restrict__ rho32) {
  int gid = blockIdx.x * 256 + threadIdx.x;  // 0..2047
  int b = gid >> 9, p = gid & 511;
  float4 acc = make_float4(0.f, 0.f, 0.f, 0.f);
#pragma unroll 4
  for (int h = 0; h < 128; h++) {
    float4 v = partial[(((b << 7) + h) << 9) + p];
    acc.x += v.x; acc.y += v.y; acc.z += v.z; acc.w += v.w;
  }
  rho32[gid] = acc;
}

// ---------------------------------------------------------------------------
// Kernel F: layers 2..4 (32x32 -> 2x2 dm) + measure. One block per batch.
// ---------------------------------------------------------------------------
__global__ __launch_bounds__(256) void finish(const float2* __restrict__ Umat,
                                              const float2* __restrict__ rho32,
                                              float* __restrict__ out) {
  __shared__ float2 rho[1024];
  __shared__ float2 r3s[64];
  __shared__ float2 r4s[16];
  int tid = threadIdx.x;
  int b = blockIdx.x;
  for (int p = tid; p < 1024; p += 256) rho[p] = rho32[(b << 10) + p];
  __syncthreads();

  float2 U[16], Uc[16];
#pragma unroll
  for (int k = 0; k < 16; k++) { U[k] = Umat[32 + k]; Uc[k] = make_float2(U[k].x, -U[k].y); }
  const int gl2[4][2] = {{4,3},{2,1},{3,2},{1,0}};
#pragma unroll
  for (int gi = 0; gi < 4; gi++) {
    int pa = gl2[gi][0], pb = gl2[gi][1];
    int p0 = pa < pb ? pa : pb, p1 = pa < pb ? pb : pa;
    int m0 = (1 << p0) - 1, m1 = (1 << p1) - 1;
    int ia = 1 << pa, ib = 1 << pb;
    {
      int j = tid >> 3, g = tid & 7;
      int idx = ((g & ~m0) << 1) | (g & m0);
      idx = ((idx & ~m1) << 1) | (idx & m1);
      float2 v0 = rho[idx * 32 + j], v1 = rho[(idx | ib) * 32 + j];
      float2 v2 = rho[(idx | ia) * 32 + j], v3 = rho[(idx | ia | ib) * 32 + j];
      gate4(v0, v1, v2, v3, U);
      rho[idx * 32 + j] = v0; rho[(idx | ib) * 32 + j] = v1;
      rho[(idx | ia) * 32 + j] = v2; rho[(idx | ia | ib) * 32 + j] = v3;
    }
    __syncthreads();
    {
      int i = tid >> 3, g = tid & 7;
      int idx = ((g & ~m0) << 1) | (g & m0);
      idx = ((idx & ~m1) << 1) | (idx & m1);
      float2 v0 = rho[i * 32 + idx], v1 = rho[i * 32 + (idx | ib)];
      float2 v2 = rho[i * 32 + (idx | ia)], v3 = rho[i * 32 + (idx | ia | ib)];
      gate4(v0, v1, v2, v3, Uc);
      rho[i * 32 + idx] = v0; rho[i * 32 + (idx | ib)] = v1;
      rho[i * 32 + (idx | ia)] = v2; rho[i * 32 + (idx | ia | ib)] = v3;
    }
    __syncthreads();
  }
  if (tid < 64) {
    int u = tid >> 3, v = tid & 7;
    float2 acc = {0.f, 0.f};
#pragma unroll
    for (int s = 0; s < 4; s++) {
      int iu = ((s >> 1) << 4) | ((u >> 2) << 3) | ((s & 1) << 2) | (((u >> 1) & 1) << 1) | (u & 1);
      int iv = ((s >> 1) << 4) | ((v >> 2) << 3) | ((s & 1) << 2) | (((v >> 1) & 1) << 1) | (v & 1);
      float2 x = rho[iu * 32 + iv];
      acc.x += x.x; acc.y += x.y;
    }
    r3s[u * 8 + v] = acc;
  }
  __syncthreads();

#pragma unroll
  for (int k = 0; k < 16; k++) { U[k] = Umat[48 + k]; Uc[k] = make_float2(U[k].x, -U[k].y); }
  const int gl3[2][2] = {{2,1},{1,0}};
#pragma unroll
  for (int gi = 0; gi < 2; gi++) {
    int pa = gl3[gi][0], pb = gl3[gi][1];
    int p0 = pa < pb ? pa : pb, p1 = pa < pb ? pb : pa;
    int m0 = (1 << p0) - 1, m1 = (1 << p1) - 1;
    int ia = 1 << pa, ib = 1 << pb;
    if (tid < 16) {
      int j = tid >> 1, g = tid & 1;
      int idx = ((g & ~m0) << 1) | (g & m0);
      idx = ((idx & ~m1) << 1) | (idx & m1);
      float2 v0 = r3s[idx * 8 + j], v1 = r3s[(idx | ib) * 8 + j];
      float2 v2 = r3s[(idx | ia) * 8 + j], v3 = r3s[(idx | ia | ib) * 8 + j];
      gate4(v0, v1, v2, v3, U);
      r3s[idx * 8 + j] = v0; r3s[(idx | ib) * 8 + j] = v1;
      r3s[(idx | ia) * 8 + j] = v2; r3s[(idx | ia | ib) * 8 + j] = v3;
    }
    __syncthreads();
    if (tid < 16) {
      int i = tid >> 1, g = tid & 1;
      int idx = ((g & ~m0) << 1) | (g & m0);
      idx = ((idx & ~m1) << 1) | (idx & m1);
      float2 v0 = r3s[i * 8 + idx], v1 = r3s[i * 8 + (idx | ib)];
      float2 v2 = r3s[i * 8 + (idx | ia)], v3 = r3s[i * 8 + (idx | ia | ib)];
      gate4(v0, v1, v2, v3, Uc);
      r3s[i * 8 + idx] = v0; r3s[i * 8 + (idx | ib)] = v1;
      r3s[i * 8 + (idx | ia)] = v2; r3s[i * 8 + (idx | ia | ib)] = v3;
    }
    __syncthreads();
  }
  if (tid < 16) {
    int u = tid >> 2, v = tid & 3;
    float2 acc = {0.f, 0.f};
#pragma unroll
    for (int s = 0; s < 2; s++) {
      float2 x = r3s[((s << 2) | u) * 8 + ((s << 2) | v)];
      acc.x += x.x; acc.y += x.y;
    }
    r4s[u * 4 + v] = acc;
  }
  __syncthreads();

#pragma unroll
  for (int k = 0; k < 16; k++) { U[k] = Umat[64 + k]; Uc[k] = make_float2(U[k].x, -U[k].y); }
  if (tid < 4) {
    int j = tid;
    float2 v0 = r4s[0 * 4 + j], v1 = r4s[1 * 4 + j], v2 = r4s[2 * 4 + j], v3 = r4s[3 * 4 + j];
    gate4(v0, v1, v2, v3, U);
    r4s[0 * 4 + j] = v0; r4s[1 * 4 + j] = v1; r4s[2 * 4 + j] = v2; r4s[3 * 4 + j] = v3;
  }
  __syncthreads();
  if (tid < 4) {
    int i = tid;
    float2 v0 = r4s[i * 4 + 0], v1 = r4s[i * 4 + 1], v2 = r4s[i * 4 + 2], v3 = r4s[i * 4 + 3];
    gate4(v0, v1, v2, v3, Uc);
    r4s[i * 4 + 0] = v0; r4s[i * 4 + 1] = v1; r4s[i * 4 + 2] = v2; r4s[i * 4 + 3] = v3;
  }
  __syncthreads();
  if (tid == 0) out[b] = r4s[0].x + r4s[10].x;
}

// ---------------------------------------------------------------------------
extern "C" void kernel_launch(void* const* d_in, const int* in_sizes, int n_in,
                              void* d_out, int out_size, void* d_ws, size_t ws_size,
                              hipStream_t stream) {
  const float* psi_re = (const float*)d_in[0];
  const float* psi_im = (const float*)d_in[1];
  const float* H_re = (const float*)d_in[2];
  const float* H_im = (const float*)d_in[3];
  float* out = (float*)d_out;

  char* ws = (char*)d_ws;
  float2* Umat = (float2*)ws;                                   // 80 float2
  float2* state = (float2*)(ws + 4096);                         // 32 MB
  float* partial = (float*)(ws + 4096 + ((size_t)1 << 25));     // 4 MB
  float* rho32 = (float*)(ws + 4096 + ((size_t)1 << 25) + ((size_t)1 << 22));  // 32 KB

  const size_t LDS_L0 = 8704 * sizeof(float2);    // padded 8192
  const size_t LDS_POOL = 8960 * sizeof(float2);  // 8*1120 stride-35 rows

  hipLaunchKernelGGL(l0_pass1, dim3(512), dim3(512), LDS_L0, stream,
                     psi_re, psi_im, H_re, H_im, Umat, state);
  hipLaunchKernelGGL(l0_pass2, dim3(512), dim3(512), LDS_L0, stream,
                     (const float2*)Umat, state);
  hipLaunchKernelGGL(pool_l1, dim3(512), dim3(512), LDS_POOL, stream,
                     (const float2*)Umat, (const float2*)state, (float2*)partial);
  hipLaunchKernelGGL(reduce_partials, dim3(8), dim3(256), 0, stream,
                     (const float4*)partial, (float4*)rho32);
  hipLaunchKernelGGL(finish, dim3(4), dim3(256), 0, stream,
                     (const float2*)Umat, (const float2*)rho32, out);
}